// Round 1
// baseline (309.630 us; speedup 1.0000x reference)
//
#include <hip/hip_runtime.h>
#include <math.h>

// Sampler: B=256 rows, V=128256 vocab.
// out[b] = (T[b]==0) ? argmax(logits[b,:])
//                    : argmax(logits[b,:]/T[b] - log(-log1p(-noise[b,:])))
// (log-space Gumbel-max; softmax denominator and row-max cancel under argmax)

constexpr int TPB = 1024;

__device__ __forceinline__ void amax_comb(float v, int i, float& bv, int& bi) {
    // np.argmax semantics: strictly greater wins; ties -> lowest index
    if (v > bv || (v == bv && i < bi)) { bv = v; bi = i; }
}

__global__ __launch_bounds__(TPB) void sampler_kernel(
    const float* __restrict__ logits,
    const float* __restrict__ temps,
    const float* __restrict__ noise,
    int* __restrict__ out, int V)
{
    const int b = blockIdx.x;
    const float temp = temps[b];
    const float invT = (temp > 0.0f) ? (1.0f / temp) : 1.0f;  // greedy rows ignore sample key
    const float4* __restrict__ lg4 = (const float4*)(logits + (size_t)b * V);
    const float4* __restrict__ nz4 = (const float4*)(noise + (size_t)b * V);
    const int V4 = V >> 2;   // V divisible by 4 (128256/4 = 32064)

    float gbv = -INFINITY; int gbi = 0x7fffffff;   // greedy best
    float sbv = -INFINITY; int sbi = 0x7fffffff;   // sample best

    for (int f = threadIdx.x; f < V4; f += TPB) {
        const float4 l = lg4[f];
        const float4 u = nz4[f];
        const int base = f << 2;
        const float lv[4] = {l.x, l.y, l.z, l.w};
        const float uv[4] = {u.x, u.y, u.z, u.w};
        #pragma unroll
        for (int k = 0; k < 4; ++k) {
            const int idx = base + k;
            amax_comb(lv[k], idx, gbv, gbi);
            // Exp(1) noise; log1pf is required for accuracy at small u
            // (small u -> huge key -> exactly the elements that win argmax)
            const float en = -log1pf(-uv[k]);
            // noise==0 -> en==0 -> logf(0) = -inf -> key = +inf, matching
            // reference's probs/0 = +inf (first-index tie-break both sides)
            const float sk = lv[k] * invT - logf(en);
            amax_comb(sk, idx, sbv, sbi);
        }
    }

    // wave (64-lane) shuffle reduction
    #pragma unroll
    for (int off = 32; off > 0; off >>= 1) {
        float ov = __shfl_down(gbv, off);
        int   oi = __shfl_down(gbi, off);
        amax_comb(ov, oi, gbv, gbi);
        ov = __shfl_down(sbv, off);
        oi = __shfl_down(sbi, off);
        amax_comb(ov, oi, sbv, sbi);
    }

    __shared__ float s_v[2][TPB / 64];
    __shared__ int   s_i[2][TPB / 64];
    const int lane = threadIdx.x & 63;
    const int wave = threadIdx.x >> 6;
    if (lane == 0) {
        s_v[0][wave] = gbv; s_i[0][wave] = gbi;
        s_v[1][wave] = sbv; s_i[1][wave] = sbi;
    }
    __syncthreads();
    if (threadIdx.x == 0) {
        #pragma unroll
        for (int w = 1; w < TPB / 64; ++w) {
            amax_comb(s_v[0][w], s_i[0][w], gbv, gbi);
            amax_comb(s_v[1][w], s_i[1][w], sbv, sbi);
        }
        out[b] = (temp == 0.0f) ? gbi : sbi;
    }
}

extern "C" void kernel_launch(void* const* d_in, const int* in_sizes, int n_in,
                              void* d_out, int out_size, void* d_ws, size_t ws_size,
                              hipStream_t stream) {
    const float* logits = (const float*)d_in[0];   // [B, V] fp32
    const float* temps  = (const float*)d_in[1];   // [B]    fp32
    const float* noise  = (const float*)d_in[2];   // [B, V] fp32
    int* out = (int*)d_out;                        // [B]    int32
    const int B = in_sizes[1];
    const int V = in_sizes[0] / B;
    sampler_kernel<<<B, TPB, 0, stream>>>(logits, temps, noise, out, V);
}

// Round 2
// 274.527 us; speedup vs baseline: 1.1279x; 1.1279x over previous
//
#include <hip/hip_runtime.h>
#include <math.h>

// Sampler: B=256 rows, V=128256 vocab.
// out[b] = (T[b]==0) ? argmax(logits[b,:])
//                    : argmax(logits[b,:]/T[b] - log(-log1p(-noise[b,:])))
// Log-space Gumbel-max: softmax denominator and row-max cancel under argmax.
// Everything computed in log2 (argmax invariant under positive scaling) so
// each log is a single HW v_log_f32 instead of ~100+ instr OCML libm calls
// (R1 post-mortem: ~290 VALU instrs/element, VALUBusy 87%, HBM 11%).

constexpr int TPB = 1024;

__device__ __forceinline__ void amax_comb(float v, int i, float& bv, int& bi) {
    // np.argmax semantics: strictly greater wins; ties -> lowest index
    if (v > bv || (v == bv && i < bi)) { bv = v; bi = i; }
}

// key = l*c - log2(-log1p(-u)), c = invT/ln2.  Absolute error <~1e-5, far
// below top-1/top-2 Gumbel key gaps.  u==0 -> en=0 -> log2 -> -inf -> +inf key
// (matches reference probs/0 = +inf; first-index tie-break both sides).
__device__ __forceinline__ float gumbel_key(float l, float u, float c) {
    // Path A (u >= 0.125): 1-u exact on the 2^-24 uniform grid; |log2(1-u)|
    // >= 0.19 so HW log relative error is harmless.
    const float w   = 1.0f - u;
    const float enw = __log2f(w) * -0.693147180559945f;   // -log(1-u)
    // Path B (u < 0.125): en/u = 1 + u/2 + u^2/3 + ... (trunc err < 6e-6 rel)
    float p = 0.16666667f;
    p = fmaf(p, u, 0.2f);
    p = fmaf(p, u, 0.25f);
    p = fmaf(p, u, 0.33333333f);
    p = fmaf(p, u, 0.5f);
    p = fmaf(p, u, 1.0f);
    const float en = (u < 0.125f) ? p * u : enw;
    return fmaf(l, c, -__log2f(en));
}

__global__ __launch_bounds__(TPB) void sampler_kernel(
    const float* __restrict__ logits,
    const float* __restrict__ temps,
    const float* __restrict__ noise,
    int* __restrict__ out, int V)
{
    const int b = blockIdx.x;
    const float temp = temps[b];
    const float4* __restrict__ lg4 = (const float4*)(logits + (size_t)b * V);
    const int V4 = V >> 2;   // V divisible by 4 (128256/4 = 32064)

    float bv = -INFINITY;
    int   bi = 0x7fffffff;

    if (temp == 0.0f) {
        // Greedy row: argmax of raw logits; skip noise load + key math.
        for (int f = threadIdx.x; f < V4; f += TPB) {
            const float4 l = lg4[f];
            const int base = f << 2;
            // indices ascend within a thread -> strict > keeps lowest index
            if (l.x > bv) { bv = l.x; bi = base;     }
            if (l.y > bv) { bv = l.y; bi = base + 1; }
            if (l.z > bv) { bv = l.z; bi = base + 2; }
            if (l.w > bv) { bv = l.w; bi = base + 3; }
        }
    } else {
        const float c = (1.0f / temp) * 1.4426950408889634f;  // invT / ln2
        const float4* __restrict__ nz4 = (const float4*)(noise + (size_t)b * V);
        for (int f = threadIdx.x; f < V4; f += TPB) {
            const float4 l = lg4[f];
            const float4 u = nz4[f];
            const int base = f << 2;
            const float k0 = gumbel_key(l.x, u.x, c);
            const float k1 = gumbel_key(l.y, u.y, c);
            const float k2 = gumbel_key(l.z, u.z, c);
            const float k3 = gumbel_key(l.w, u.w, c);
            if (k0 > bv) { bv = k0; bi = base;     }
            if (k1 > bv) { bv = k1; bi = base + 1; }
            if (k2 > bv) { bv = k2; bi = base + 2; }
            if (k3 > bv) { bv = k3; bi = base + 3; }
        }
    }

    // wave (64-lane) shuffle reduction, with lowest-index tie-break
    #pragma unroll
    for (int off = 32; off > 0; off >>= 1) {
        const float ov = __shfl_down(bv, off);
        const int   oi = __shfl_down(bi, off);
        amax_comb(ov, oi, bv, bi);
    }

    __shared__ float s_v[TPB / 64];
    __shared__ int   s_i[TPB / 64];
    const int lane = threadIdx.x & 63;
    const int wave = threadIdx.x >> 6;
    if (lane == 0) { s_v[wave] = bv; s_i[wave] = bi; }
    __syncthreads();
    if (threadIdx.x == 0) {
        #pragma unroll
        for (int w = 1; w < TPB / 64; ++w) amax_comb(s_v[w], s_i[w], bv, bi);
        out[b] = bi;
    }
}

extern "C" void kernel_launch(void* const* d_in, const int* in_sizes, int n_in,
                              void* d_out, int out_size, void* d_ws, size_t ws_size,
                              hipStream_t stream) {
    const float* logits = (const float*)d_in[0];   // [B, V] fp32
    const float* temps  = (const float*)d_in[1];   // [B]    fp32
    const float* noise  = (const float*)d_in[2];   // [B, V] fp32
    int* out = (int*)d_out;                        // [B]    int32
    const int B = in_sizes[1];
    const int V = in_sizes[0] / B;
    sampler_kernel<<<B, TPB, 0, stream>>>(logits, temps, noise, out, V);
}